// Round 7
// baseline (105.570 us; speedup 1.0000x reference)
//
#include <hip/hip_runtime.h>
#include <math.h>

// Problem constants
constexpr int R_ = 8;
constexpr int B_ = 16;
constexpr int D_ = 32;
constexpr int H_ = 128;
constexpr int N_ = 2048;
constexpr int F_ = 256;
constexpr int O_ = 64;               // 2*D
constexpr float HLP_ = 0.9189385332046727f;

typedef float f32x4 __attribute__((ext_vector_type(4)));
typedef short bf16x8 __attribute__((ext_vector_type(8)));
typedef unsigned uint32x4 __attribute__((ext_vector_type(4)));

// pack two fp32 -> one dword of two bf16 in ONE VALU op (R17-verified).
__device__ __forceinline__ unsigned pk2(float lo, float hi) {
    unsigned r;
    asm("v_cvt_pk_bf16_f32 %0, %1, %2" : "=v"(r) : "v"(lo), "v"(hi));
    return r;
}

// R18: 4-lane-group (c, c+16, c+32, c+48) sum via permlane swaps on the VALU
// pipe — replaces 2x __shfl_xor (ds_bpermute, LDS latency) in the serial tail.
__device__ __forceinline__ float qsum(float v) {
    unsigned a = __builtin_bit_cast(unsigned, v), b = a;
    asm("v_permlane32_swap_b32 %0, %1" : "+v"(a), "+v"(b));
    float s = __builtin_bit_cast(float, a) + __builtin_bit_cast(float, b);
    unsigned c2 = __builtin_bit_cast(unsigned, s), d2 = c2;
    asm("v_permlane16_swap_b32 %0, %1" : "+v"(c2), "+v"(d2));
    return __builtin_bit_cast(float, c2) + __builtin_bit_cast(float, d2);
}

// ---------------------------------------------------------------------------
// R18: phase-1 deep pipeline + setprio + VALU epilogue reduction.
//   R17 post-mortem: -4us real (cvt_pk + barrier removal). Kernel ~16us vs
//   ~10us structural floor (MFMA 7.2us + phase-1 ~3). Gap = phase-1 serial
//   latency (7 slab loads at depth-1 pipelining) + phase-2 overlap slack.
//   (1) 4 wv buffers; W1,W2k0,W2k1,W2k2 loads issued BEFORE barrier-1;
//       W2k3,W3lo,W3hi right after; stores interleaved. Masks folded into
//       loads as selects (drops 48 mask VGPRs + pack multiplies).
//   (2) s_setprio(1) around GEMM2+GEMM3 MFMA: phase 2 is barrier-free ->
//       waves drift independently (attn-like regime where T5 paid +4-7%).
//   (3) qsum permlane reduction replaces shfl_xor(16/32) ds_bpermutes.
//
// R17: v_cvt_pk_bf16_f32 pk2 (1 op); no barrier after phase 1 (WA2 writes
//   ordered by the B2 barrier; phase 2 never writes LDS).
// R16: butterfly (VERIFIED): C-pair -> B-frag via permlane32/16_swap:
//   swap32(d,e); swap16(d,e) -> frag {d0,d1,e0,e1} = B-frag k=8q'+j.
// R15: computed masks (M2 from h_deg arithmetic; M3 via degs ballot from M1).
// R12: XCD-aware (rb, hf) mapping. R11: 256x512 = 1 blk/CU, 2 waves/SIMD.
//
// __launch_bounds__(512,2): VGPR cap 256; GEMM2 peak ~244.
// LDS: WA2 32 KB + stg 20 KB = 52 KB.
// ---------------------------------------------------------------------------
__global__ __launch_bounds__(512, 2)
void flow_all(const float* __restrict__ x,
              const float* __restrict__ W1, const float* __restrict__ W2,
              const float* __restrict__ W3,
              const float* __restrict__ M1, const float* __restrict__ M2,
              const float* __restrict__ M3,
              const int* __restrict__ ridx,
              float* __restrict__ out)
{
    __shared__ __align__(16) unsigned short WA2[16384];     // 32 KB: W2 A-frags
    __shared__ __align__(16) unsigned short stg[2][5120];   // 20 KB staging
    __shared__ int degs[32];                                // deg_in per d

    // R12: XCD-aware decomposition.
    const int bid  = blockIdx.x;
    const int xcd  = bid & 7;
    const int slot = bid >> 3;           // 0..31 within XCD
    const int rb   = xcd * 16 + (slot >> 1);   // network 0..127, 16/XCD
    const int hf   = slot & 1;           // half of N
    const int r    = rb >> 4;            // == xcd

    const int t    = threadIdx.x;
    const int lane = t & 63;
    const int w    = t >> 6;             // wave 0..7
    const int q    = lane >> 4;
    const int c    = lane & 15;

    // lane's base sample row; wave w owns rows [hf*1024 + w*128, +128)
    const int nbase = hf * 1024 + w * 128 + c;
    const int xoff  = r * 32 + q * 8;    // contiguous feature base

    auto xload = [&](int row, float* g) {
        const float* p0 = x + (size_t)row * F_ + xoff;
        float4 f0 = *(const float4*)p0;
        float4 f1 = *(const float4*)(p0 + 4);
        g[0] = f0.x; g[1] = f0.y; g[2] = f0.z; g[3] = f0.w;
        g[4] = f1.x; g[5] = f1.y; g[6] = f1.z; g[7] = f1.w;
    };

    // prefetch pass-0 rows (2 tiles) before weight packing
    float gA[8], gB[8];
    xload(nbase, gA);
    xload(nbase + 16, gB);

    // ---- phase 1: W1/W3 -> register frags; W2 -> WA2 frags ----
    bf16x8 a1[8], a3[4][4];
    {
        const float* W1b = W1 + (size_t)rb * 32 * 128;
        const float* M1b = M1 + (size_t)rb * 32 * 128;
        const float* W2b = W2 + (size_t)rb * 128 * 128;
        const float* W3b = W3 + (size_t)rb * 128 * 64;

        const int pm = t & 127, pkh = t >> 7;   // 128-wide slabs: col, row-octet (0..3)
        const int qm = t & 63,  qk  = t >> 6;   // 64-wide superslabs: col, row-octet (0..7)
        // W3 column permutation (dest col -> source col), R6-R10 validated
        int osrc;
        {
            int dp = qm >> 1, pb = qm & 1;
            int dsrc = ((dp >> 1) & 3) * 8 + (dp >> 3) * 2 + (dp & 1);
            osrc = dsrc * 2 + pb;
        }

        float wv0[8], wv1[8], wv2[8], wv3[8], mv0[8];

        // W1 + M1 (masks from global for s0 only)
        auto load_w1 = [&](float* wvv, float* mvv) {
            const float* wp = W1b + (size_t)(pkh * 8) * 128 + pm;
            const float* mp = M1b + (size_t)(pkh * 8) * 128 + pm;
#pragma unroll
            for (int e = 0; e < 8; ++e) { wvv[e] = wp[(size_t)e * 128]; mvv[e] = mp[(size_t)e * 128]; }
        };
        // W2 slab j (rows j*32+pkh*8+e), M2 computed and folded in
        auto load_w2 = [&](int j, float* wvv) {
            const float* wp = W2b + (size_t)(j * 32 + pkh * 8) * 128 + pm;
            const int kb = j * 32 + pkh * 8;
            const int pmod = pm % 31;
#pragma unroll
            for (int e = 0; e < 8; ++e) {
                float v = wp[(size_t)e * 128];
                wvv[e] = (((kb + e) % 31) <= pmod) ? v : 0.f;
            }
        };
        // W3 half ss (rows ss*64+qk*8+e, col osrc), M3 computed from degs
        auto load_w3 = [&](int ss, float* wvv) {
            const float* wp = W3b + (size_t)(ss * 64 + qk * 8) * 64 + osrc;
            const int kb = ss * 64 + qk * 8;
            const int degq = degs[osrc >> 1];
#pragma unroll
            for (int e = 0; e < 8; ++e) {
                float v = wp[(size_t)e * 64];
                wvv[e] = ((((kb + e) % 31) + 1) < degq) ? v : 0.f;
            }
        };
        auto pack4m = [&](const float* wvv, const float* mvv, unsigned* u) {
#pragma unroll
            for (int e2 = 0; e2 < 4; ++e2)
                u[e2] = pk2(wvv[2 * e2] * mvv[2 * e2], wvv[2 * e2 + 1] * mvv[2 * e2 + 1]);
        };
        auto pack4 = [&](const float* wvv, unsigned* u) {
#pragma unroll
            for (int e2 = 0; e2 < 4; ++e2)
                u[e2] = pk2(wvv[2 * e2], wvv[2 * e2 + 1]);
        };
        auto store_stg128 = [&](unsigned short* st, const float* wvv, const float* mvv) {
            unsigned u[4]; pack4m(wvv, mvv, u);
            *(uint32x4*)&st[pm * 40 + pkh * 8] = (uint32x4){u[0], u[1], u[2], u[3]};
        };
        auto store_stg64 = [&](unsigned short* st, const float* wvv) {
            unsigned u[4]; pack4(wvv, u);
            *(uint32x4*)&st[qm * 72 + qk * 8] = (uint32x4){u[0], u[1], u[2], u[3]};
        };
        // direct A-frag pack: rows klocal = pkh*8+e -> q = pkh, j = e;
        // frag (kt, mt = pm>>4), lane = pkh*16 + (pm&15): ONE b128 write.
        auto store_wa2 = [&](int kt, const float* wvv) {
            unsigned u[4]; pack4(wvv, u);
            int mt = pm >> 4, cc = pm & 15;
            *(uint32x4*)&WA2[(((kt * 8 + mt) * 64) + pkh * 16 + cc) * 8] = (uint32x4){u[0], u[1], u[2], u[3]};
        };

        // --- deep pipeline: 4 loads in flight before barrier-1 ---
        load_w1(wv0, mv0);
        // derive deg_in from M1: even waves hold pm = lane (0..63); row
        // d = pkh*8+e; for h in 0..30 M1[d,h] = (h >= deg_in[d]-1) ->
        // deg = ctz(ballot & 0x7FFFFFFF) + 1, or 32 if no bit set.
        if ((w & 1) == 0) {
#pragma unroll
            for (int e = 0; e < 8; ++e) {
                unsigned long long bb = __ballot(mv0[e] > 0.5f);
                if (lane == 0) {
                    unsigned long long mm = bb & 0x7FFFFFFFull;
                    degs[pkh * 8 + e] = mm ? ((int)__builtin_ctzll(mm) + 1) : 32;
                }
            }
        }
        load_w2(0, wv1);
        load_w2(1, wv2);
        load_w2(2, wv3);
        store_stg128(stg[0], wv0, mv0);
        __syncthreads();                 // B1: stg0 + degs published
#pragma unroll
        for (int mt = 0; mt < 8; ++mt)
            a1[mt] = *(const bf16x8*)&stg[0][(mt * 16 + c) * 40 + q * 8];
        load_w2(3, wv0);                 // wv0 free (consumed by store_stg128)
        store_wa2(0, wv1);
        load_w3(0, wv1);                 // needs degs (after B1) ✓
        store_wa2(1, wv2);
        load_w3(1, wv2);
        store_wa2(2, wv3);
        store_wa2(3, wv0);
        // W3 k0..63 -> stg1 -> a3[0..1]   (all WA2 writes precede B2)
        store_stg64(stg[1], wv1);
        __syncthreads();                 // B2
#pragma unroll
        for (int mt3 = 0; mt3 < 4; ++mt3) {
            a3[0][mt3] = *(const bf16x8*)&stg[1][(mt3 * 16 + c) * 72 + 0  + q * 8];
            a3[1][mt3] = *(const bf16x8*)&stg[1][(mt3 * 16 + c) * 72 + 32 + q * 8];
        }
        // W3 k64..127 -> stg0 (safe: all a1 reads drained by B2)
        store_stg64(stg[0], wv2);
        __syncthreads();                 // B3
#pragma unroll
        for (int mt3 = 0; mt3 < 4; ++mt3) {
            a3[2][mt3] = *(const bf16x8*)&stg[0][(mt3 * 16 + c) * 72 + 0  + q * 8];
            a3[3][mt3] = *(const bf16x8*)&stg[0][(mt3 * 16 + c) * 72 + 32 + q * 8];
        }
    }
    // No barrier here (R17): WA2 writes ordered by B2; phase 2 reads only.

    // C-pair (tiles 2kt, 2kt+1) -> B-frag(kt) via VALU butterfly (relu+pack).
    // swap32(d, e): d = [t0q0,t0q1|t1q0,t1q1], e = [t0q2,t0q3|t1q2,t1q3]
    // swap16(d, e): d = [t0q0,t0q2|t1q0,t1q2], e = [t0q1,t0q3|t1q1,t1q3]
    // -> frag {d0,d1,e0,e1}: lane q' holds k = 8q'+j, j = 0..7.  (R16-verified)
    auto xpose_relu = [&](const f32x4& t0, const f32x4& t1) -> bf16x8 {
        unsigned d0 = pk2(fmaxf(t0[0], 0.f), fmaxf(t0[1], 0.f));
        unsigned d1 = pk2(fmaxf(t0[2], 0.f), fmaxf(t0[3], 0.f));
        unsigned e0 = pk2(fmaxf(t1[0], 0.f), fmaxf(t1[1], 0.f));
        unsigned e1 = pk2(fmaxf(t1[2], 0.f), fmaxf(t1[3], 0.f));
        asm("v_permlane32_swap_b32 %0, %1" : "+v"(d0), "+v"(e0));
        asm("v_permlane32_swap_b32 %0, %1" : "+v"(d1), "+v"(e1));
        asm("v_permlane16_swap_b32 %0, %1" : "+v"(d0), "+v"(e0));
        asm("v_permlane16_swap_b32 %0, %1" : "+v"(d1), "+v"(e1));
        uint32x4 u = {d0, d1, e0, e1};
        return __builtin_bit_cast(bf16x8, u);
    };

    const f32x4 z = {0.f, 0.f, 0.f, 0.f};

    // ---- phase 2: 4 passes x 2 tiles, zero barriers, zero h-LDS ----
#pragma unroll 1
    for (int p = 0; p < 4; ++p) {
        uint32x4 uA = {pk2(gA[0], gA[1]), pk2(gA[2], gA[3]), pk2(gA[4], gA[5]), pk2(gA[6], gA[7])};
        uint32x4 uB = {pk2(gB[0], gB[1]), pk2(gB[2], gB[3]), pk2(gB[4], gB[5]), pk2(gB[6], gB[7])};
        bf16x8 xbA = __builtin_bit_cast(bf16x8, uA);
        bf16x8 xbB = __builtin_bit_cast(bf16x8, uB);

        // GEMM1 (K=32): 16 MFMA, a1 in regs; C -> b2 frags in regs
        bf16x8 b2A[4], b2B[4];
#pragma unroll
        for (int kt = 0; kt < 4; ++kt) {
            f32x4 c0A = __builtin_amdgcn_mfma_f32_16x16x32_bf16(a1[2 * kt],     xbA, z, 0, 0, 0);
            f32x4 c1A = __builtin_amdgcn_mfma_f32_16x16x32_bf16(a1[2 * kt + 1], xbA, z, 0, 0, 0);
            f32x4 c0B = __builtin_amdgcn_mfma_f32_16x16x32_bf16(a1[2 * kt],     xbB, z, 0, 0, 0);
            f32x4 c1B = __builtin_amdgcn_mfma_f32_16x16x32_bf16(a1[2 * kt + 1], xbB, z, 0, 0, 0);
            b2A[kt] = xpose_relu(c0A, c1A);
            b2B[kt] = xpose_relu(c0B, c1B);
        }

        // R18: favor this wave while in the MFMA-dense region (barrier-free
        // phase 2 -> waves at different phases; scheduler can arbitrate).
        __builtin_amdgcn_s_setprio(1);

        // GEMM2 (K=128): 64 MFMA; W2 frags streamed from WA2 (only DS ops)
        f32x4 c2A[8], c2B[8];
#pragma unroll
        for (int mt = 0; mt < 8; ++mt) { c2A[mt] = z; c2B[mt] = z; }
#pragma unroll
        for (int kt = 0; kt < 4; ++kt) {
#pragma unroll
            for (int g = 0; g < 2; ++g) {     // stage 4 A-frags at a time
                bf16x8 a2t[4];
#pragma unroll
                for (int m4 = 0; m4 < 4; ++m4)
                    a2t[m4] = *(const bf16x8*)&WA2[((kt * 8 + g * 4 + m4) * 64 + lane) * 8];
#pragma unroll
                for (int m4 = 0; m4 < 4; ++m4) {
                    int mt = g * 4 + m4;
                    c2A[mt] = __builtin_amdgcn_mfma_f32_16x16x32_bf16(a2t[m4], b2A[kt], c2A[mt], 0, 0, 0);
                    c2B[mt] = __builtin_amdgcn_mfma_f32_16x16x32_bf16(a2t[m4], b2B[kt], c2B[mt], 0, 0, 0);
                }
            }
        }

        // h2 C -> b3 frags in regs
        bf16x8 b3A[4], b3B[4];
#pragma unroll
        for (int kt = 0; kt < 4; ++kt) {
            b3A[kt] = xpose_relu(c2A[2 * kt], c2A[2 * kt + 1]);
            b3B[kt] = xpose_relu(c2B[2 * kt], c2B[2 * kt + 1]);
        }

        // GEMM3 (K=128, O=64 permuted): 32 MFMA, a3 in regs + MAF epilogue
        {
            f32x4 c3A[4], c3B[4];
#pragma unroll
            for (int mt3 = 0; mt3 < 4; ++mt3) { c3A[mt3] = z; c3B[mt3] = z; }
#pragma unroll
            for (int kt = 0; kt < 4; ++kt) {
#pragma unroll
                for (int mt3 = 0; mt3 < 4; ++mt3) {
                    c3A[mt3] = __builtin_amdgcn_mfma_f32_16x16x32_bf16(a3[kt][mt3], b3A[kt], c3A[mt3], 0, 0, 0);
                    c3B[mt3] = __builtin_amdgcn_mfma_f32_16x16x32_bf16(a3[kt][mt3], b3B[kt], c3B[mt3], 0, 0, 0);
                }
            }
            __builtin_amdgcn_s_setprio(0);

            // epilogue: slot o = mt3*16+q*4+reg; rr=reg>>1 -> source
            // d = q*8 + mt3*2 + rr -> x is the lane's own f32 gA/gB[mt3*2+rr]
            float llA = 0.f, llB = 0.f;
#pragma unroll
            for (int mt3 = 0; mt3 < 4; ++mt3) {
#pragma unroll
                for (int rr = 0; rr < 2; ++rr) {
                    float shA = c3A[mt3][rr * 2], lsA = c3A[mt3][rr * 2 + 1];
                    float shB = c3B[mt3][rr * 2], lsB = c3B[mt3][rr * 2 + 1];
                    float u0 = (gA[mt3 * 2 + rr] - shA) * __expf(-lsA);
                    float u1 = (gB[mt3 * 2 + rr] - shB) * __expf(-lsB);
                    llA += fmaf(-0.5f * u0, u0, -HLP_ - lsA);
                    llB += fmaf(-0.5f * u1, u1, -HLP_ - lsB);
                }
            }

            // next-pass x prefetch at the x-dead point: covered by the
            // qsum + store + backedge + pk2 pack (+2 waves/SIMD TLP)
            if (p < 3) {
                xload(nbase + (p + 1) * 32, gA);
                xload(nbase + (p + 1) * 32 + 16, gB);
            }

            llA = qsum(llA);
            llB = qsum(llB);
            if (q == 0) {
                int n = nbase + p * 32;
                out[(size_t)n * 128 + rb]        = llA;
                out[(size_t)(n + 16) * 128 + rb] = llB;
            }
        }
    }
}

extern "C" void kernel_launch(void* const* d_in, const int* in_sizes, int n_in,
                              void* d_out, int out_size, void* d_ws, size_t ws_size,
                              hipStream_t stream) {
    const float* x   = (const float*)d_in[0];
    const float* W1  = (const float*)d_in[1];
    const float* W2  = (const float*)d_in[2];
    const float* W3  = (const float*)d_in[3];
    const float* M1  = (const float*)d_in[4];
    const float* M2  = (const float*)d_in[5];
    const float* M3  = (const float*)d_in[6];
    const int*  ridx = (const int*)d_in[7];
    float* out = (float*)d_out;

    flow_all<<<dim3(256), dim3(512), 0, stream>>>(x, W1, W2, W3, M1, M2, M3, ridx, out);
}

// Round 8
// 104.386 us; speedup vs baseline: 1.0113x; 1.0113x over previous
//
#include <hip/hip_runtime.h>
#include <math.h>

// Problem constants
constexpr int R_ = 8;
constexpr int B_ = 16;
constexpr int D_ = 32;
constexpr int H_ = 128;
constexpr int N_ = 2048;
constexpr int F_ = 256;
constexpr int O_ = 64;               // 2*D
constexpr float HLP_ = 0.9189385332046727f;

typedef float f32x4 __attribute__((ext_vector_type(4)));
typedef short bf16x8 __attribute__((ext_vector_type(8)));
typedef unsigned uint32x4 __attribute__((ext_vector_type(4)));

// pack two fp32 -> one dword of two bf16 in ONE VALU op (R17-verified).
__device__ __forceinline__ unsigned pk2(float lo, float hi) {
    unsigned r;
    asm("v_cvt_pk_bf16_f32 %0, %1, %2" : "=v"(r) : "v"(lo), "v"(hi));
    return r;
}

// 4-lane-group (c, c+16, c+32, c+48) sum via permlane swaps on the VALU
// pipe — replaces 2x __shfl_xor (ds_bpermute latency) in the serial tail.
__device__ __forceinline__ float qsum(float v) {
    unsigned a = __builtin_bit_cast(unsigned, v), b = a;
    asm("v_permlane32_swap_b32 %0, %1" : "+v"(a), "+v"(b));
    float s = __builtin_bit_cast(float, a) + __builtin_bit_cast(float, b);
    unsigned c2 = __builtin_bit_cast(unsigned, s), d2 = c2;
    asm("v_permlane16_swap_b32 %0, %1" : "+v"(c2), "+v"(d2));
    return __builtin_bit_cast(float, c2) + __builtin_bit_cast(float, d2);
}

// ---------------------------------------------------------------------------
// R19: REVERT R18's deep-pipeline + setprio (regression -> 105.6; mechanisms:
//   (a) hipcc drains vmcnt(0) at every s_barrier, so pre-B1 load batching
//   forces an all-wave drain AT the barrier — anti-pipelining; (b) setprio
//   at 2 near-lockstep waves/SIMD starves the co-wave's prefetch/epilogue,
//   the m190 GEMM-regression mechanism).
//   KEPT from R18 (pure local instruction reductions, no scheduling change):
//   * qsum: permlane-swap tail reduction (VALU) replacing 4 ds_bpermute.
//   * mask-fold: M2/M3 masks applied as a select in the load (w = m? w : 0),
//     dropping the separate mask registers and pack multiplies (0/1 masks ->
//     bit-identical).
//   Skeleton is EXACT R17 (verified 103.7): same slab interleave, barriers,
//   prefetch placement.
//
// R17: v_cvt_pk_bf16_f32 pk2 (1 op); no barrier after phase 1.
// R16: butterfly (VERIFIED): C-pair -> B-frag via permlane32/16_swap:
//   swap32(d,e); swap16(d,e) -> frag {d0,d1,e0,e1} = B-frag k=8q'+j.
// R15: computed masks (M2 from h_deg arithmetic; M3 via degs ballot from M1).
// R12: XCD-aware (rb, hf) mapping. R11: 256x512 = 1 blk/CU, 2 waves/SIMD.
//
// __launch_bounds__(512,2): VGPR cap 256; GEMM2 peak ~240.
// LDS: WA2 32 KB + stg 20 KB = 52 KB.
// ---------------------------------------------------------------------------
__global__ __launch_bounds__(512, 2)
void flow_all(const float* __restrict__ x,
              const float* __restrict__ W1, const float* __restrict__ W2,
              const float* __restrict__ W3,
              const float* __restrict__ M1, const float* __restrict__ M2,
              const float* __restrict__ M3,
              const int* __restrict__ ridx,
              float* __restrict__ out)
{
    __shared__ __align__(16) unsigned short WA2[16384];     // 32 KB: W2 A-frags
    __shared__ __align__(16) unsigned short stg[2][5120];   // 20 KB staging
    __shared__ int degs[32];                                // deg_in per d

    // R12: XCD-aware decomposition.
    const int bid  = blockIdx.x;
    const int xcd  = bid & 7;
    const int slot = bid >> 3;           // 0..31 within XCD
    const int rb   = xcd * 16 + (slot >> 1);   // network 0..127, 16/XCD
    const int hf   = slot & 1;           // half of N
    const int r    = rb >> 4;            // == xcd

    const int t    = threadIdx.x;
    const int lane = t & 63;
    const int w    = t >> 6;             // wave 0..7
    const int q    = lane >> 4;
    const int c    = lane & 15;

    // lane's base sample row; wave w owns rows [hf*1024 + w*128, +128)
    const int nbase = hf * 1024 + w * 128 + c;
    const int xoff  = r * 32 + q * 8;    // contiguous feature base

    auto xload = [&](int row, float* g) {
        const float* p0 = x + (size_t)row * F_ + xoff;
        float4 f0 = *(const float4*)p0;
        float4 f1 = *(const float4*)(p0 + 4);
        g[0] = f0.x; g[1] = f0.y; g[2] = f0.z; g[3] = f0.w;
        g[4] = f1.x; g[5] = f1.y; g[6] = f1.z; g[7] = f1.w;
    };

    // prefetch pass-0 rows (2 tiles) before weight packing
    float gA[8], gB[8];
    xload(nbase, gA);
    xload(nbase + 16, gB);

    // ---- phase 1: W1/W3 -> register frags; W2 -> WA2 frags ----
    bf16x8 a1[8], a3[4][4];
    {
        const float* W1b = W1 + (size_t)rb * 32 * 128;
        const float* M1b = M1 + (size_t)rb * 32 * 128;
        const float* W2b = W2 + (size_t)rb * 128 * 128;
        const float* W3b = W3 + (size_t)rb * 128 * 64;

        const int pm = t & 127, pkh = t >> 7;   // 128-wide slabs: col, row-octet (0..3)
        const int qm = t & 63,  qk  = t >> 6;   // 64-wide superslabs: col, row-octet (0..7)
        // W3 column permutation (dest col -> source col), R6-R10 validated
        int osrc;
        {
            int dp = qm >> 1, pb = qm & 1;
            int dsrc = ((dp >> 1) & 3) * 8 + (dp >> 3) * 2 + (dp & 1);
            osrc = dsrc * 2 + pb;
        }

        float wv[2][8], mv0[8];
        // slabs: 0 = W1 (M1 from global); 1..4 = W2 kt 0..3 (M2 folded in);
        //        5,6 = W3 halves (M3 folded in, from derived deg_in)
        auto slab_load = [&](int s, float* wvv, float* mvv) {
            if (s == 0) {
                const float* wp = W1b + (size_t)(pkh * 8) * 128 + pm;
                const float* mp = M1b + (size_t)(pkh * 8) * 128 + pm;
#pragma unroll
                for (int e = 0; e < 8; ++e) { wvv[e] = wp[(size_t)e * 128]; mvv[e] = mp[(size_t)e * 128]; }
            } else if (s <= 4) {
                const float* wp = W2b + (size_t)((s - 1) * 32 + pkh * 8) * 128 + pm;
                const int kb = (s - 1) * 32 + pkh * 8;
                const int pmod = pm % 31;
#pragma unroll
                for (int e = 0; e < 8; ++e) {
                    float v = wp[(size_t)e * 128];
                    wvv[e] = (((kb + e) % 31) <= pmod) ? v : 0.f;     // M2 folded
                }
            } else {
                int ss = s - 5;
                const float* wp = W3b + (size_t)(ss * 64 + qk * 8) * 64 + osrc;
                const int kb = ss * 64 + qk * 8;
                const int degq = degs[osrc >> 1];
#pragma unroll
                for (int e = 0; e < 8; ++e) {
                    float v = wp[(size_t)e * 64];
                    wvv[e] = ((((kb + e) % 31) + 1) < degq) ? v : 0.f; // M3 folded
                }
            }
        };
        auto pack4m = [&](const float* wvv, const float* mvv, unsigned* u) {
#pragma unroll
            for (int e2 = 0; e2 < 4; ++e2)
                u[e2] = pk2(wvv[2 * e2] * mvv[2 * e2], wvv[2 * e2 + 1] * mvv[2 * e2 + 1]);
        };
        auto pack4 = [&](const float* wvv, unsigned* u) {
#pragma unroll
            for (int e2 = 0; e2 < 4; ++e2)
                u[e2] = pk2(wvv[2 * e2], wvv[2 * e2 + 1]);
        };
        auto store_stg128 = [&](unsigned short* st, const float* wvv, const float* mvv) {
            unsigned u[4]; pack4m(wvv, mvv, u);
            *(uint32x4*)&st[pm * 40 + pkh * 8] = (uint32x4){u[0], u[1], u[2], u[3]};
        };
        auto store_stg64 = [&](unsigned short* st, const float* wvv) {
            unsigned u[4]; pack4(wvv, u);
            *(uint32x4*)&st[qm * 72 + qk * 8] = (uint32x4){u[0], u[1], u[2], u[3]};
        };
        // direct A-frag pack: rows klocal = pkh*8+e -> q = pkh, j = e;
        // frag (kt, mt = pm>>4), lane = pkh*16 + (pm&15): ONE b128 write.
        auto store_wa2 = [&](int kt, const float* wvv) {
            unsigned u[4]; pack4(wvv, u);
            int mt = pm >> 4, cc = pm & 15;
            *(uint32x4*)&WA2[(((kt * 8 + mt) * 64) + pkh * 16 + cc) * 8] = (uint32x4){u[0], u[1], u[2], u[3]};
        };

        slab_load(0, wv[0], mv0);
        // derive deg_in from M1: even waves hold pm = lane (0..63); row
        // d = pkh*8+e; for h in 0..30 M1[d,h] = (h >= deg_in[d]-1) ->
        // deg = ctz(ballot & 0x7FFFFFFF) + 1, or 32 if no bit set.
        if ((w & 1) == 0) {
#pragma unroll
            for (int e = 0; e < 8; ++e) {
                unsigned long long bb = __ballot(mv0[e] > 0.5f);
                if (lane == 0) {
                    unsigned long long mm = bb & 0x7FFFFFFFull;
                    degs[pkh * 8 + e] = mm ? ((int)__builtin_ctzll(mm) + 1) : 32;
                }
            }
        }
        slab_load(1, wv[1], nullptr);
        // s0: W1 -> stg0 -> a1   (barrier also publishes degs[] for s5/s6)
        store_stg128(stg[0], wv[0], mv0);
        __syncthreads();                 // B1
#pragma unroll
        for (int mt = 0; mt < 8; ++mt)
            a1[mt] = *(const bf16x8*)&stg[0][(mt * 16 + c) * 40 + q * 8];
        // s1..4: W2 -> WA2 (no barriers; covered by s5's barrier)
        slab_load(2, wv[0], nullptr);
        store_wa2(0, wv[1]);
        slab_load(3, wv[1], nullptr);
        store_wa2(1, wv[0]);
        slab_load(4, wv[0], nullptr);
        store_wa2(2, wv[1]);
        slab_load(5, wv[1], nullptr);    // W3 lo (degs published by B1)
        store_wa2(3, wv[0]);
        slab_load(6, wv[0], nullptr);    // W3 hi
        // s5: W3 k0..63 -> stg1 -> a3[0..1]
        store_stg64(stg[1], wv[1]);
        __syncthreads();                 // B2 (also orders all WA2 writes)
#pragma unroll
        for (int mt3 = 0; mt3 < 4; ++mt3) {
            a3[0][mt3] = *(const bf16x8*)&stg[1][(mt3 * 16 + c) * 72 + 0  + q * 8];
            a3[1][mt3] = *(const bf16x8*)&stg[1][(mt3 * 16 + c) * 72 + 32 + q * 8];
        }
        // s6: W3 k64..127 -> stg0 (safe: all a1 reads precede B2)
        store_stg64(stg[0], wv[0]);
        __syncthreads();                 // B3
#pragma unroll
        for (int mt3 = 0; mt3 < 4; ++mt3) {
            a3[2][mt3] = *(const bf16x8*)&stg[0][(mt3 * 16 + c) * 72 + 0  + q * 8];
            a3[3][mt3] = *(const bf16x8*)&stg[0][(mt3 * 16 + c) * 72 + 32 + q * 8];
        }
    }
    // No barrier here (R17-verified): WA2 writes ordered by B2; phase 2
    // reads LDS only.

    // C-pair (tiles 2kt, 2kt+1) -> B-frag(kt) via VALU butterfly (relu+pack).
    // swap32(d, e): d = [t0q0,t0q1|t1q0,t1q1], e = [t0q2,t0q3|t1q2,t1q3]
    // swap16(d, e): d = [t0q0,t0q2|t1q0,t1q2], e = [t0q1,t0q3|t1q1,t1q3]
    // -> frag {d0,d1,e0,e1}: lane q' holds k = 8q'+j, j = 0..7.  (R16-verified)
    auto xpose_relu = [&](const f32x4& t0, const f32x4& t1) -> bf16x8 {
        unsigned d0 = pk2(fmaxf(t0[0], 0.f), fmaxf(t0[1], 0.f));
        unsigned d1 = pk2(fmaxf(t0[2], 0.f), fmaxf(t0[3], 0.f));
        unsigned e0 = pk2(fmaxf(t1[0], 0.f), fmaxf(t1[1], 0.f));
        unsigned e1 = pk2(fmaxf(t1[2], 0.f), fmaxf(t1[3], 0.f));
        asm("v_permlane32_swap_b32 %0, %1" : "+v"(d0), "+v"(e0));
        asm("v_permlane32_swap_b32 %0, %1" : "+v"(d1), "+v"(e1));
        asm("v_permlane16_swap_b32 %0, %1" : "+v"(d0), "+v"(e0));
        asm("v_permlane16_swap_b32 %0, %1" : "+v"(d1), "+v"(e1));
        uint32x4 u = {d0, d1, e0, e1};
        return __builtin_bit_cast(bf16x8, u);
    };

    const f32x4 z = {0.f, 0.f, 0.f, 0.f};

    // ---- phase 2: 4 passes x 2 tiles, zero barriers, zero h-LDS ----
#pragma unroll 1
    for (int p = 0; p < 4; ++p) {
        uint32x4 uA = {pk2(gA[0], gA[1]), pk2(gA[2], gA[3]), pk2(gA[4], gA[5]), pk2(gA[6], gA[7])};
        uint32x4 uB = {pk2(gB[0], gB[1]), pk2(gB[2], gB[3]), pk2(gB[4], gB[5]), pk2(gB[6], gB[7])};
        bf16x8 xbA = __builtin_bit_cast(bf16x8, uA);
        bf16x8 xbB = __builtin_bit_cast(bf16x8, uB);

        // GEMM1 (K=32): 16 MFMA, a1 in regs; C -> b2 frags in regs
        bf16x8 b2A[4], b2B[4];
#pragma unroll
        for (int kt = 0; kt < 4; ++kt) {
            f32x4 c0A = __builtin_amdgcn_mfma_f32_16x16x32_bf16(a1[2 * kt],     xbA, z, 0, 0, 0);
            f32x4 c1A = __builtin_amdgcn_mfma_f32_16x16x32_bf16(a1[2 * kt + 1], xbA, z, 0, 0, 0);
            f32x4 c0B = __builtin_amdgcn_mfma_f32_16x16x32_bf16(a1[2 * kt],     xbB, z, 0, 0, 0);
            f32x4 c1B = __builtin_amdgcn_mfma_f32_16x16x32_bf16(a1[2 * kt + 1], xbB, z, 0, 0, 0);
            b2A[kt] = xpose_relu(c0A, c1A);
            b2B[kt] = xpose_relu(c0B, c1B);
        }

        // GEMM2 (K=128): 64 MFMA; W2 frags streamed from WA2 (only DS ops)
        f32x4 c2A[8], c2B[8];
#pragma unroll
        for (int mt = 0; mt < 8; ++mt) { c2A[mt] = z; c2B[mt] = z; }
#pragma unroll
        for (int kt = 0; kt < 4; ++kt) {
#pragma unroll
            for (int g = 0; g < 2; ++g) {     // stage 4 A-frags at a time
                bf16x8 a2t[4];
#pragma unroll
                for (int m4 = 0; m4 < 4; ++m4)
                    a2t[m4] = *(const bf16x8*)&WA2[((kt * 8 + g * 4 + m4) * 64 + lane) * 8];
#pragma unroll
                for (int m4 = 0; m4 < 4; ++m4) {
                    int mt = g * 4 + m4;
                    c2A[mt] = __builtin_amdgcn_mfma_f32_16x16x32_bf16(a2t[m4], b2A[kt], c2A[mt], 0, 0, 0);
                    c2B[mt] = __builtin_amdgcn_mfma_f32_16x16x32_bf16(a2t[m4], b2B[kt], c2B[mt], 0, 0, 0);
                }
            }
        }

        // h2 C -> b3 frags in regs
        bf16x8 b3A[4], b3B[4];
#pragma unroll
        for (int kt = 0; kt < 4; ++kt) {
            b3A[kt] = xpose_relu(c2A[2 * kt], c2A[2 * kt + 1]);
            b3B[kt] = xpose_relu(c2B[2 * kt], c2B[2 * kt + 1]);
        }

        // GEMM3 (K=128, O=64 permuted): 32 MFMA, a3 in regs + MAF epilogue
        {
            f32x4 c3A[4], c3B[4];
#pragma unroll
            for (int mt3 = 0; mt3 < 4; ++mt3) { c3A[mt3] = z; c3B[mt3] = z; }
#pragma unroll
            for (int kt = 0; kt < 4; ++kt) {
#pragma unroll
                for (int mt3 = 0; mt3 < 4; ++mt3) {
                    c3A[mt3] = __builtin_amdgcn_mfma_f32_16x16x32_bf16(a3[kt][mt3], b3A[kt], c3A[mt3], 0, 0, 0);
                    c3B[mt3] = __builtin_amdgcn_mfma_f32_16x16x32_bf16(a3[kt][mt3], b3B[kt], c3B[mt3], 0, 0, 0);
                }
            }
            // epilogue: slot o = mt3*16+q*4+reg; rr=reg>>1 -> source
            // d = q*8 + mt3*2 + rr -> x is the lane's own f32 gA/gB[mt3*2+rr]
            float llA = 0.f, llB = 0.f;
#pragma unroll
            for (int mt3 = 0; mt3 < 4; ++mt3) {
#pragma unroll
                for (int rr = 0; rr < 2; ++rr) {
                    float shA = c3A[mt3][rr * 2], lsA = c3A[mt3][rr * 2 + 1];
                    float shB = c3B[mt3][rr * 2], lsB = c3B[mt3][rr * 2 + 1];
                    float u0 = (gA[mt3 * 2 + rr] - shA) * __expf(-lsA);
                    float u1 = (gB[mt3 * 2 + rr] - shB) * __expf(-lsB);
                    llA += fmaf(-0.5f * u0, u0, -HLP_ - lsA);
                    llB += fmaf(-0.5f * u1, u1, -HLP_ - lsB);
                }
            }

            // next-pass x prefetch at the x-dead point: covered by the
            // qsum + store + backedge + pk2 pack (+2 waves/SIMD TLP)
            if (p < 3) {
                xload(nbase + (p + 1) * 32, gA);
                xload(nbase + (p + 1) * 32 + 16, gB);
            }

            llA = qsum(llA);
            llB = qsum(llB);
            if (q == 0) {
                int n = nbase + p * 32;
                out[(size_t)n * 128 + rb]        = llA;
                out[(size_t)(n + 16) * 128 + rb] = llB;
            }
        }
    }
}

extern "C" void kernel_launch(void* const* d_in, const int* in_sizes, int n_in,
                              void* d_out, int out_size, void* d_ws, size_t ws_size,
                              hipStream_t stream) {
    const float* x   = (const float*)d_in[0];
    const float* W1  = (const float*)d_in[1];
    const float* W2  = (const float*)d_in[2];
    const float* W3  = (const float*)d_in[3];
    const float* M1  = (const float*)d_in[4];
    const float* M2  = (const float*)d_in[5];
    const float* M3  = (const float*)d_in[6];
    const int*  ridx = (const int*)d_in[7];
    float* out = (float*)d_out;

    flow_all<<<dim3(256), dim3(512), 0, stream>>>(x, W1, W2, W3, M1, M2, M3, ridx, out);
}